// Round 3
// baseline (38.286 us; speedup 1.0000x reference)
//
#include <hip/hip_runtime.h>
#include <hip/hip_bf16.h>

// loss = mean_b (out_b - label_b)^2,
// out_b = sqrt(s_ab) / (s_aa^(1/4) * s_bb^(1/4)),
// s_xy  = sum_{s,t} (X_s . Y_t)^2  (Frobenius^2 of X Y^T).
//
// 10 WGs per batch (256 thr, 4 waves), one 64x64 tile-job per wave:
//   t0: A-lo self   (diag)    t3: B-lo self    t6..t9: A-half x B-half
//   t1: A-lo x A-hi (w2)      t4: B-lo x B-hi
//   t2: A-hi self             t5: B-hi self
// Diag WGs stage 128 rows (16 KB LDS), others 256 rows (32 KB).
// Single-buffered LDS; occupancy (4-5 blocks/CU) provides the overlap.

typedef short short8  __attribute__((ext_vector_type(8)));
typedef short short4_ __attribute__((ext_vector_type(4)));
typedef float f32x16  __attribute__((ext_vector_type(16)));

constexpr int BATCH = 128;
constexpr int S     = 256;
constexpr int D     = 384;
constexpr int BK    = 64;     // K per LDS chunk
constexpr int NCH   = D / BK; // 6

// per type: {matX, offX, matY, offY, diag, w}
__device__ const signed char TT[10][6] = {
  {0,0, 0,0, 1, 1},   // t0: A-lo self
  {0,0, 0,1, 0, 2},   // t1: A-lo x A-hi (counts transpose too)
  {0,1, 0,1, 1, 1},   // t2: A-hi self
  {1,0, 1,0, 1, 1},   // t3: B-lo self
  {1,0, 1,1, 0, 2},   // t4: B-lo x B-hi
  {1,1, 1,1, 1, 1},   // t5: B-hi self
  {0,0, 1,0, 0, 1},   // t6: A-lo x B-lo
  {0,0, 1,1, 0, 1},   // t7: A-lo x B-hi
  {0,1, 1,0, 0, 1},   // t8: A-hi x B-lo
  {0,1, 1,1, 0, 1},   // t9: A-hi x B-hi
};

__device__ __forceinline__ short bf16_of(float f) {
    __hip_bfloat16 h = __float2bfloat16(f);
    short s; __builtin_memcpy(&s, &h, 2); return s;
}

// 8B-subchunk XOR-16 swizzled fragment read (proven 0-conflict in R1).
__device__ __forceinline__ short8 frag_read(const short* L, int row, int ks, int lane) {
    const int u0 = (ks * 2 + (lane >> 5)) * 2;
    const int x  = row & 15;
    const int rb = row * BK;
    short8 f;
    *(short4_*)&f     = *(const short4_*)&L[rb + ((u0    ) ^ x) * 4];
    ((short4_*)&f)[1] = *(const short4_*)&L[rb + ((u0 + 1) ^ x) * 4];
    return f;
}

#define MFMA(a,b,c) __builtin_amdgcn_mfma_f32_32x32x16_bf16(a, b, c, 0, 0, 0)

__global__ __launch_bounds__(256, 4)
void gram(const float* __restrict__ A, const float* __restrict__ B,
          float* __restrict__ ws)
{
    __shared__ short lds[S * BK];   // 32 KiB (diag WGs use lower 16 KiB)

    // bid = local*8 + xcd; all 10 WGs of a batch share an XCD (L2 reuse).
    const int bid   = blockIdx.x;
    const int xcd   = bid & 7;
    const int local = bid >> 3;
    const int bl    = local / 10;
    const int type  = local - bl * 10;
    const int batch = xcd * 16 + bl;

    const signed char* t = TT[type];
    const bool diag = t[4] != 0;
    const size_t mb = (size_t)batch * S * D;
    const float* S0 = (t[0] ? B : A) + mb + (size_t)t[1] * 128 * D;  // lds rows 0-127
    const float* S1 = (t[2] ? B : A) + mb + (size_t)t[3] * 128 * D;  // lds rows 128-255

    const int tid  = threadIdx.x;
    const int lane = tid & 63;
    const int wv   = tid >> 6;
    const int l31  = lane & 31;

    // staging coords: fixed per thread; row = i*16 + tr each iteration.
    const int tr = tid >> 4;          // 0..15
    const int u  = tid & 15;          // 8B subchunk within 64-col row
    short* wbase = &lds[tr * BK + ((u ^ tr) << 2)];
    const float* g0 = S0 + tr * D + u * 4;
    const float* g1 = S1 + tr * D + u * 4;

    // per-wave job (one 64x64 tile): units within the 4x64-row stack.
    int xu, yu;
    if (diag) { xu = (wv == 3); yu = (wv != 0); }       // (0,0),(0,1),(0,1),(1,1)
    else      { xu = wv >> 1;   yu = 2 + (wv & 1); }    // (0,2),(0,3),(1,2),(1,3)
    const float w = (float)t[5];

    const int xr0 = xu * 64 + l31, xr1 = xr0 + 32;
    const int yr0 = yu * 64 + l31, yr1 = yr0 + 32;

    f32x16 a00 = {}, a01 = {}, a10 = {}, a11 = {};

    for (int kc = 0; kc < NCH; ++kc) {
        const int co = kc * BK;
        // ---- stage rows 0-127 (G0) ----
        #pragma unroll
        for (int i = 0; i < 8; ++i) {
            float4 v = *(const float4*)(g0 + (size_t)i * 16 * D + co);
            short4_ p;
            p[0] = bf16_of(v.x); p[1] = bf16_of(v.y);
            p[2] = bf16_of(v.z); p[3] = bf16_of(v.w);
            *(short4_*)(wbase + i * 16 * BK) = p;
        }
        // ---- stage rows 128-255 (G1) unless diag ----
        if (!diag) {
            #pragma unroll
            for (int i = 0; i < 8; ++i) {
                float4 v = *(const float4*)(g1 + (size_t)i * 16 * D + co);
                short4_ p;
                p[0] = bf16_of(v.x); p[1] = bf16_of(v.y);
                p[2] = bf16_of(v.z); p[3] = bf16_of(v.w);
                *(short4_*)(wbase + (128 + i * 16) * BK) = p;
            }
        }
        __syncthreads();
        // ---- compute: 4 ks x 4 MFMA (2x2 of 32x32) ----
        #pragma unroll
        for (int ks = 0; ks < 4; ++ks) {
            short8 xa0 = frag_read(lds, xr0, ks, lane);
            short8 xa1 = frag_read(lds, xr1, ks, lane);
            short8 yb0 = frag_read(lds, yr0, ks, lane);
            short8 yb1 = frag_read(lds, yr1, ks, lane);
            a00 = MFMA(xa0, yb0, a00); a01 = MFMA(xa0, yb1, a01);
            a10 = MFMA(xa1, yb0, a10); a11 = MFMA(xa1, yb1, a11);
        }
        __syncthreads();   // protect lds before next-stage overwrite
    }

    // ---- square-accumulate (x weight) -> one scalar per WG ----
    float sum = 0.f;
    #pragma unroll
    for (int i = 0; i < 16; ++i)
        sum += a00[i]*a00[i] + a01[i]*a01[i] + a10[i]*a10[i] + a11[i]*a11[i];
    sum *= w;
    #pragma unroll
    for (int o = 32; o > 0; o >>= 1) sum += __shfl_xor(sum, o, 64);
    float* red = (float*)lds;
    if (lane == 0) red[wv] = sum;
    __syncthreads();
    if (tid == 0) ws[bid] = red[0] + red[1] + red[2] + red[3];
}

__global__ void finalize(const float* __restrict__ ws,
                         const float* __restrict__ labels,
                         float* __restrict__ out)
{
    __shared__ float red[128];
    const int b = threadIdx.x;                 // one thread per batch
    const int base = (b & 15) * 10, xc = b >> 4;
    #define W(ty) ws[((base + (ty)) << 3) | xc]
    const float s_aa = W(0) + W(1) + W(2);
    const float s_bb = W(3) + W(4) + W(5);
    const float s_ab = W(6) + W(7) + W(8) + W(9);
    #undef W
    const float outb = sqrtf(s_ab) / (sqrtf(sqrtf(s_aa)) * sqrtf(sqrtf(s_bb)));
    const float d    = outb - labels[b];
    red[b] = d * d * (1.0f / 128.0f);
    __syncthreads();
    for (int off = 64; off > 0; off >>= 1) {
        if (b < off) red[b] += red[b + off];
        __syncthreads();
    }
    if (b == 0) out[0] = red[0];
}

extern "C" void kernel_launch(void* const* d_in, const int* in_sizes, int n_in,
                              void* d_out, int out_size, void* d_ws, size_t ws_size,
                              hipStream_t stream)
{
    const float* A      = (const float*)d_in[0];
    const float* B      = (const float*)d_in[1];
    const float* labels = (const float*)d_in[2];
    float* ws = (float*)d_ws;   // 1280 floats, all written every launch

    gram<<<dim3(BATCH * 10), dim3(256), 0, stream>>>(A, B, ws);
    finalize<<<dim3(1), dim3(128), 0, stream>>>(ws, labels, (float*)d_out);
}